// Round 5
// baseline (368.486 us; speedup 1.0000x reference)
//
#include <hip/hip_runtime.h>

#define CLAMP_MIN_F (-10.0f)
#define CLAMP_MAX_F (10.0f)
#define BATCH 8
#define R_LOG 7          // 128 nodes per bucket
#define RNODES 128
#define EPB 8192         // edges per binning block
#define MAXK 1024        // max buckets supported by scan kernel

// ---------------- prep: transpose (B,N) -> (N,B) for chemT/o_preT/E_T ------
__global__ void prep_kernel(const float* __restrict__ chem_in,
                            const float* __restrict__ o_pre,
                            const float* __restrict__ E,
                            float* __restrict__ chemT,
                            float* __restrict__ o_preT,
                            float* __restrict__ E_T,
                            int N) {
    int n = blockIdx.x * blockDim.x + threadIdx.x;
    if (n >= N) return;
    float c[BATCH], o[BATCH], ee[BATCH];
    #pragma unroll
    for (int b = 0; b < BATCH; ++b) {
        c[b]  = chem_in[b * N + n];
        o[b]  = o_pre[b * N + n];
        ee[b] = E[b * N + n];
    }
    float4* cp = (float4*)&chemT[(size_t)n * BATCH];
    cp[0] = make_float4(c[0], c[1], c[2], c[3]);
    cp[1] = make_float4(c[4], c[5], c[6], c[7]);
    float4* op = (float4*)&o_preT[(size_t)n * BATCH];
    op[0] = make_float4(o[0], o[1], o[2], o[3]);
    op[1] = make_float4(o[4], o[5], o[6], o[7]);
    float4* ep = (float4*)&E_T[(size_t)n * BATCH];
    ep[0] = make_float4(ee[0], ee[1], ee[2], ee[3]);
    ep[1] = make_float4(ee[4], ee[5], ee[6], ee[7]);
}

// ---------------- pass 1: per-block histogram over buckets ------------------
__global__ void hist_kernel(const int* __restrict__ dst,
                            unsigned* __restrict__ hist,
                            int edges, int KPAD) {
    __shared__ unsigned sh[MAXK];
    int bid = blockIdx.x;
    for (int k = threadIdx.x; k < KPAD; k += blockDim.x) sh[k] = 0u;
    __syncthreads();
    int start = bid * EPB;
    int end = min(edges, start + EPB);
    for (int i = start + threadIdx.x; i < end; i += blockDim.x)
        atomicAdd(&sh[((unsigned)dst[i]) >> R_LOG], 1u);
    __syncthreads();
    for (int k = threadIdx.x; k < KPAD; k += blockDim.x)
        hist[(size_t)bid * KPAD + k] = sh[k];
}

// ---------------- pass 2a: column sums (per-bucket totals) ------------------
__global__ void colsum_kernel(const unsigned* __restrict__ hist,
                              unsigned* __restrict__ colSum,
                              int NB, int KPAD) {
    int k = blockIdx.x * blockDim.x + threadIdx.x;
    if (k >= KPAD) return;
    unsigned s = 0;
    for (int b = 0; b < NB; ++b) s += hist[(size_t)b * KPAD + k];
    colSum[k] = s;
}

// ---------------- pass 2b: exclusive scan over bucket totals ----------------
// single block of MAXK threads (Hillis-Steele)
__global__ void scan_kernel(const unsigned* __restrict__ colSum,
                            unsigned* __restrict__ base,
                            int KPAD) {
    __shared__ unsigned a[MAXK];
    __shared__ unsigned b[MAXK];
    int t = threadIdx.x;
    a[t] = (t < KPAD) ? colSum[t] : 0u;
    __syncthreads();
    unsigned* cur = a;
    unsigned* nxt = b;
    for (int off = 1; off < MAXK; off <<= 1) {
        unsigned v = cur[t];
        if (t >= off) v += cur[t - off];
        nxt[t] = v;
        __syncthreads();
        unsigned* tmp = cur; cur = nxt; nxt = tmp;
    }
    // cur = inclusive scan
    base[t + 1] = cur[t];
    if (t == 0) base[0] = 0u;
}

// ---------------- pass 2c: per-(block,bucket) starting offsets --------------
__global__ void offs_kernel(const unsigned* __restrict__ hist,
                            const unsigned* __restrict__ base,
                            unsigned* __restrict__ offs,
                            int NB, int KPAD) {
    int k = blockIdx.x * blockDim.x + threadIdx.x;
    if (k >= KPAD) return;
    unsigned run = base[k];
    for (int b = 0; b < NB; ++b) {
        offs[(size_t)b * KPAD + k] = run;
        run += hist[(size_t)b * KPAD + k];
    }
}

// ---------------- pass 3: scatter edges into bucket-sorted records ----------
__global__ void scatter_kernel(const int* __restrict__ src,
                               const int* __restrict__ dst,
                               const float* __restrict__ w,
                               const unsigned* __restrict__ offs,
                               int4* __restrict__ recS,
                               int edges, int KPAD) {
    __shared__ unsigned loffs[MAXK];
    int bid = blockIdx.x;
    for (int k = threadIdx.x; k < KPAD; k += blockDim.x)
        loffs[k] = offs[(size_t)bid * KPAD + k];
    __syncthreads();
    int start = bid * EPB;
    int end = min(edges, start + EPB);
    for (int i = start + threadIdx.x; i < end; i += blockDim.x) {
        int d = dst[i];
        int s = src[i];
        float wv = w[i];
        unsigned k = ((unsigned)d) >> R_LOG;
        unsigned pos = atomicAdd(&loffs[k], 1u);
        recS[pos] = make_int4(d, s, __float_as_int(wv), 0);
    }
}

// ---------------- pass 4: per-bucket accumulate (no global atomics) ---------
__global__ void accum_kernel(const int4* __restrict__ recS,
                             const unsigned* __restrict__ base,
                             const float* __restrict__ o_preT,
                             const float* __restrict__ E_T,
                             float* __restrict__ chemT,
                             int N) {
    __shared__ float acc[RNODES * 9];   // stride 9 to spread LDS banks
    int k = blockIdx.x;
    int nodeStart = k << R_LOG;
    int nodeCnt = min(RNODES, N - nodeStart);
    for (int i = threadIdx.x; i < RNODES * 9; i += blockDim.x) acc[i] = 0.f;
    __syncthreads();
    unsigned b0 = base[k], b1 = base[k + 1];
    int b = threadIdx.x & 7;
    for (unsigned r = b0 + (threadIdx.x >> 3); r < b1; r += (blockDim.x >> 3)) {
        int4 rec = recS[r];             // x=dst, y=src, z=w bits
        float Oj = o_preT[((size_t)rec.y << 3) + b];
        float En = E_T[((size_t)rec.x << 3) + b];
        float diff = Oj - En;
        float sg = (diff > 0.0f) ? 1.0f : ((diff < 0.0f) ? -1.0f : 0.0f);
        float contrib = Oj * __int_as_float(rec.z) * sg;
        atomicAdd(&acc[(rec.x - nodeStart) * 9 + b], contrib);
    }
    __syncthreads();
    for (int i = threadIdx.x; i < nodeCnt * BATCH; i += blockDim.x) {
        int n = i >> 3, bb = i & 7;
        chemT[(((size_t)(nodeStart + n)) << 3) + bb] += acc[n * 9 + bb];
    }
}

// ---------------- finalize ---------------------------------------------------
__global__ void finalize_nb(const float* __restrict__ E,      // (B,N)
                            const float* __restrict__ chemT,  // (N,B)
                            const float* __restrict__ thr,
                            const float* __restrict__ decay,
                            float* __restrict__ new_o,        // (B,N)
                            float* __restrict__ new_e,        // (B,N)
                            int N) {
    int n = blockIdx.x * blockDim.x + threadIdx.x;
    if (n >= N) return;
    const float4* cp = (const float4*)&chemT[(size_t)n * BATCH];
    float4 c0 = cp[0], c1 = cp[1];
    float c[BATCH] = {c0.x, c0.y, c0.z, c0.w, c1.x, c1.y, c1.z, c1.w};
    float t = thr[n];
    float dc = decay[n];
    #pragma unroll
    for (int b = 0; b < BATCH; ++b) {
        int i = b * N + n;
        float e = E[i];
        float S = fminf(fmaxf(e + c[b], CLAMP_MIN_F), CLAMP_MAX_F);
        bool gt = S > t;
        float no = fmaxf(S - t, 0.0f);
        float ne = gt ? no : ((S == e) ? (e - dc) : S);
        new_o[i] = no;
        new_e[i] = ne;
    }
}

// ---------------- fallback: R3 atomic path ----------------------------------
__global__ void edge_scatter_eb(const int* __restrict__ src,
                                const int* __restrict__ dst,
                                const float* __restrict__ w,
                                const float* __restrict__ o_preT,
                                const float* __restrict__ E_T,
                                float* __restrict__ chemT,
                                int edges) {
    int t = blockIdx.x * blockDim.x + threadIdx.x;
    int e = t >> 3;
    int b = t & 7;
    if (e >= edges) return;
    int s = src[e]; int d = dst[e]; float we = w[e];
    float Oj = o_preT[(size_t)s * BATCH + b];
    float En = E_T[(size_t)d * BATCH + b];
    float diff = Oj - En;
    float sg = (diff > 0.0f) ? 1.0f : ((diff < 0.0f) ? -1.0f : 0.0f);
    atomicAdd(&chemT[(size_t)d * BATCH + b], Oj * we * sg);
}

static inline size_t align256(size_t x) { return (x + 255) & ~(size_t)255; }

extern "C" void kernel_launch(void* const* d_in, const int* in_sizes, int n_in,
                              void* d_out, int out_size, void* d_ws, size_t ws_size,
                              hipStream_t stream) {
    const float* chem_influence = (const float*)d_in[0];
    const float* E              = (const float*)d_in[1];
    const int*   src            = (const int*)d_in[3];
    const int*   dst            = (const int*)d_in[4];
    const float* w              = (const float*)d_in[5];
    const float* o_pre          = (const float*)d_in[6];
    const float* threshold      = (const float*)d_in[7];
    const float* decay          = (const float*)d_in[8];

    const int edges = in_sizes[3];
    const int BN    = in_sizes[0];   // B * N
    const int N     = in_sizes[7];   // threshold is (N,)

    float* new_o = (float*)d_out;
    float* new_e = (float*)d_out + BN;

    const int TB = 256;
    int nblk = (N + TB - 1) / TB;

    const int K    = (N + RNODES - 1) >> R_LOG;        // buckets
    const int KPAD = (K + 15) & ~15;
    const int NB   = (edges + EPB - 1) / EPB;          // binning blocks

    // ws layout
    size_t off = 0;
    size_t chemT_off  = off; off += align256((size_t)BN * 4);
    size_t opreT_off  = off; off += align256((size_t)BN * 4);
    size_t ET_off     = off; off += align256((size_t)BN * 4);
    size_t base_off   = off; off += align256((size_t)(MAXK + 1) * 4);
    size_t colsum_off = off; off += align256((size_t)MAXK * 4);
    size_t hist_off   = off; off += align256((size_t)NB * KPAD * 4);
    size_t offs_off   = off; off += align256((size_t)NB * KPAD * 4);
    size_t rec_off    = off; off += align256((size_t)edges * 16);
    size_t need = off;

    char* wsb = (char*)d_ws;

    if (K <= MAXK && ws_size >= need) {
        float*    chemT  = (float*)(wsb + chemT_off);
        float*    o_preT = (float*)(wsb + opreT_off);
        float*    E_T    = (float*)(wsb + ET_off);
        unsigned* base   = (unsigned*)(wsb + base_off);
        unsigned* colSum = (unsigned*)(wsb + colsum_off);
        unsigned* hist   = (unsigned*)(wsb + hist_off);
        unsigned* offs   = (unsigned*)(wsb + offs_off);
        int4*     recS   = (int4*)(wsb + rec_off);

        prep_kernel<<<nblk, TB, 0, stream>>>(chem_influence, o_pre, E,
                                             chemT, o_preT, E_T, N);
        hist_kernel<<<NB, TB, 0, stream>>>(dst, hist, edges, KPAD);
        colsum_kernel<<<(KPAD + TB - 1) / TB, TB, 0, stream>>>(hist, colSum, NB, KPAD);
        scan_kernel<<<1, MAXK, 0, stream>>>(colSum, base, KPAD);
        offs_kernel<<<(KPAD + TB - 1) / TB, TB, 0, stream>>>(hist, base, offs, NB, KPAD);
        scatter_kernel<<<NB, TB, 0, stream>>>(src, dst, w, offs, recS, edges, KPAD);
        accum_kernel<<<K, TB, 0, stream>>>(recS, base, o_preT, E_T, chemT, N);
        finalize_nb<<<nblk, TB, 0, stream>>>(E, chemT, threshold, decay,
                                             new_o, new_e, N);
    } else if (ws_size >= 3 * (size_t)BN * 4) {
        // R3 fallback: single chemT + device atomics
        float* chemT  = (float*)d_ws;
        float* o_preT = chemT + BN;
        float* E_T    = o_preT + BN;
        prep_kernel<<<nblk, TB, 0, stream>>>(chem_influence, o_pre, E,
                                             chemT, o_preT, E_T, N);
        long long ethreads = (long long)edges * BATCH;
        int gblk = (int)((ethreads + TB - 1) / TB);
        edge_scatter_eb<<<gblk, TB, 0, stream>>>(src, dst, w, o_preT, E_T,
                                                 chemT, edges);
        finalize_nb<<<nblk, TB, 0, stream>>>(E, chemT, threshold, decay,
                                             new_o, new_e, N);
    }
}

// Round 6
// 353.437 us; speedup vs baseline: 1.0426x; 1.0426x over previous
//
#include <hip/hip_runtime.h>

#define CLAMP_MIN_F (-10.0f)
#define CLAMP_MAX_F (10.0f)
#define BATCH 8
#define R_LOG 6          // 64 nodes per bucket
#define RNODES 64
#define EPB 8192         // edges per binning block
#define MAX2K 2048       // scan capacity (K must be <= 2047)

// ---------------- prep: transpose (B,N) -> (N,B) for o_preT / E_T ----------
__global__ void prep2_kernel(const float* __restrict__ o_pre,
                             const float* __restrict__ E,
                             float* __restrict__ o_preT,
                             float* __restrict__ E_T,
                             int N) {
    int n = blockIdx.x * blockDim.x + threadIdx.x;
    if (n >= N) return;
    float o[BATCH], ee[BATCH];
    #pragma unroll
    for (int b = 0; b < BATCH; ++b) {
        o[b]  = o_pre[b * N + n];
        ee[b] = E[b * N + n];
    }
    float4* op = (float4*)&o_preT[(size_t)n * BATCH];
    op[0] = make_float4(o[0], o[1], o[2], o[3]);
    op[1] = make_float4(o[4], o[5], o[6], o[7]);
    float4* ep = (float4*)&E_T[(size_t)n * BATCH];
    ep[0] = make_float4(ee[0], ee[1], ee[2], ee[3]);
    ep[1] = make_float4(ee[4], ee[5], ee[6], ee[7]);
}

// ---------------- pass 1: per-block histogram over buckets ------------------
__global__ void hist_kernel(const int* __restrict__ dst,
                            unsigned* __restrict__ hist,
                            int edges, int KPAD) {
    __shared__ unsigned sh[MAX2K];
    int bid = blockIdx.x;
    for (int k = threadIdx.x; k < KPAD; k += blockDim.x) sh[k] = 0u;
    __syncthreads();
    int start = bid * EPB;
    int end = min(edges, start + EPB);
    for (int i = start + threadIdx.x; i < end; i += blockDim.x)
        atomicAdd(&sh[((unsigned)dst[i]) >> R_LOG], 1u);
    __syncthreads();
    for (int k = threadIdx.x; k < KPAD; k += blockDim.x)
        hist[(size_t)bid * KPAD + k] = sh[k];
}

// ---------------- pass 2a: column sums (per-bucket totals) ------------------
__global__ void colsum_kernel(const unsigned* __restrict__ hist,
                              unsigned* __restrict__ colSum,
                              int NB, int KPAD) {
    int k = blockIdx.x * blockDim.x + threadIdx.x;
    if (k >= KPAD) return;
    unsigned s = 0;
    for (int b = 0; b < NB; ++b) s += hist[(size_t)b * KPAD + k];
    colSum[k] = s;
}

// ---------------- pass 2b: exclusive scan over bucket totals (<=2048) -------
// single block of 1024 threads, 2 elements per thread
__global__ void scan2_kernel(const unsigned* __restrict__ colSum,
                             unsigned* __restrict__ base,
                             int KPAD) {
    __shared__ unsigned s1[1024];
    __shared__ unsigned s2[1024];
    int t = threadIdx.x;
    unsigned a = (2 * t     < KPAD) ? colSum[2 * t]     : 0u;
    unsigned b = (2 * t + 1 < KPAD) ? colSum[2 * t + 1] : 0u;
    s1[t] = a + b;
    __syncthreads();
    unsigned* cur = s1;
    unsigned* nxt = s2;
    for (int off = 1; off < 1024; off <<= 1) {
        unsigned v = cur[t];
        if (t >= off) v += cur[t - off];
        nxt[t] = v;
        __syncthreads();
        unsigned* tmp = cur; cur = nxt; nxt = tmp;
    }
    unsigned incl = cur[t];
    unsigned excl = incl - (a + b);
    base[2 * t]     = excl;
    base[2 * t + 1] = excl + a;
    if (t == 1023) base[2048] = incl;
}

// ---------------- pass 2c: per-(block,bucket) starting offsets --------------
__global__ void offs_kernel(const unsigned* __restrict__ hist,
                            const unsigned* __restrict__ base,
                            unsigned* __restrict__ offs,
                            int NB, int KPAD) {
    int k = blockIdx.x * blockDim.x + threadIdx.x;
    if (k >= KPAD) return;
    unsigned run = base[k];
    for (int b = 0; b < NB; ++b) {
        offs[(size_t)b * KPAD + k] = run;
        run += hist[(size_t)b * KPAD + k];
    }
}

// ---------------- pass 3: scatter edges into 8B bucket-sorted records -------
// key = (dst_local:6 bits << 26) | src (src < 2^26)
__global__ void scatter_kernel(const int* __restrict__ src,
                               const int* __restrict__ dst,
                               const float* __restrict__ w,
                               const unsigned* __restrict__ offs,
                               int2* __restrict__ recS,
                               int edges, int KPAD) {
    __shared__ unsigned loffs[MAX2K];
    int bid = blockIdx.x;
    for (int k = threadIdx.x; k < KPAD; k += blockDim.x)
        loffs[k] = offs[(size_t)bid * KPAD + k];
    __syncthreads();
    int start = bid * EPB;
    int end = min(edges, start + EPB);
    for (int i = start + threadIdx.x; i < end; i += blockDim.x) {
        int d = dst[i];
        int s = src[i];
        float wv = w[i];
        unsigned k = ((unsigned)d) >> R_LOG;
        unsigned pos = atomicAdd(&loffs[k], 1u);
        unsigned key = (((unsigned)d & (RNODES - 1)) << 26) | (unsigned)s;
        recS[pos] = make_int2((int)key, __float_as_int(wv));
    }
}

// ------- pass 4: per-bucket accumulate + fused finalize (no global atomics) -
__global__ void accum_kernel(const int2* __restrict__ recS,
                             const unsigned* __restrict__ base,
                             const float* __restrict__ o_preT,   // (N,B)
                             const float* __restrict__ E_T,      // (N,B)
                             const float* __restrict__ chem_in,  // (B,N)
                             const float* __restrict__ thr,
                             const float* __restrict__ decay,
                             float* __restrict__ new_o,          // (B,N)
                             float* __restrict__ new_e,          // (B,N)
                             int N) {
    __shared__ float acc[RNODES * 9];   // stride 9 to spread LDS banks
    int k = blockIdx.x;
    int ns = k << R_LOG;
    int cnt = min(RNODES, N - ns);
    for (int i = threadIdx.x; i < RNODES * 9; i += blockDim.x) acc[i] = 0.f;
    __syncthreads();
    unsigned b0 = base[k], b1 = base[k + 1];
    int b = threadIdx.x & 7;
    int g = threadIdx.x >> 3;
    int ng = blockDim.x >> 3;
    unsigned r = b0 + g;
    // 2-way unrolled: two independent record->gather chains per group
    for (; r + (unsigned)ng < b1; r += 2u * ng) {
        int2 rec0 = recS[r];
        int2 rec1 = recS[r + ng];
        unsigned k0 = (unsigned)rec0.x, k1 = (unsigned)rec1.x;
        float Oj0 = o_preT[((size_t)(k0 & 0x3FFFFFFu) << 3) + b];
        float Oj1 = o_preT[((size_t)(k1 & 0x3FFFFFFu) << 3) + b];
        int dl0 = (int)(k0 >> 26), dl1 = (int)(k1 >> 26);
        float En0 = E_T[((size_t)(ns + dl0) << 3) + b];
        float En1 = E_T[((size_t)(ns + dl1) << 3) + b];
        float d0 = Oj0 - En0, d1 = Oj1 - En1;
        float sg0 = (d0 > 0.f) ? 1.f : ((d0 < 0.f) ? -1.f : 0.f);
        float sg1 = (d1 > 0.f) ? 1.f : ((d1 < 0.f) ? -1.f : 0.f);
        atomicAdd(&acc[dl0 * 9 + b], Oj0 * __int_as_float(rec0.y) * sg0);
        atomicAdd(&acc[dl1 * 9 + b], Oj1 * __int_as_float(rec1.y) * sg1);
    }
    if (r < b1) {
        int2 rec = recS[r];
        unsigned kk = (unsigned)rec.x;
        float Oj = o_preT[((size_t)(kk & 0x3FFFFFFu) << 3) + b];
        int dl = (int)(kk >> 26);
        float En = E_T[((size_t)(ns + dl) << 3) + b];
        float d = Oj - En;
        float sg = (d > 0.f) ? 1.f : ((d < 0.f) ? -1.f : 0.f);
        atomicAdd(&acc[dl * 9 + b], Oj * __int_as_float(rec.y) * sg);
    }
    __syncthreads();
    // fused finalize over this bucket's nodes (exclusive ownership)
    for (int n = threadIdx.x; n < cnt; n += blockDim.x) {
        float t  = thr[ns + n];
        float dc = decay[ns + n];
        #pragma unroll
        for (int bb = 0; bb < BATCH; ++bb) {
            float e = E_T[((size_t)(ns + n) << 3) + bb];
            float S = e + chem_in[(size_t)bb * N + ns + n] + acc[n * 9 + bb];
            S = fminf(fmaxf(S, CLAMP_MIN_F), CLAMP_MAX_F);
            bool gt = S > t;
            float no = fmaxf(S - t, 0.f);
            float ne = gt ? no : ((S == e) ? (e - dc) : S);
            new_o[(size_t)bb * N + ns + n] = no;
            new_e[(size_t)bb * N + ns + n] = ne;
        }
    }
}

// ---------------- fallback: R3 atomic path ----------------------------------
__global__ void prep_kernel(const float* __restrict__ chem_in,
                            const float* __restrict__ o_pre,
                            const float* __restrict__ E,
                            float* __restrict__ chemT,
                            float* __restrict__ o_preT,
                            float* __restrict__ E_T,
                            int N) {
    int n = blockIdx.x * blockDim.x + threadIdx.x;
    if (n >= N) return;
    float c[BATCH], o[BATCH], ee[BATCH];
    #pragma unroll
    for (int b = 0; b < BATCH; ++b) {
        c[b]  = chem_in[b * N + n];
        o[b]  = o_pre[b * N + n];
        ee[b] = E[b * N + n];
    }
    float4* cp = (float4*)&chemT[(size_t)n * BATCH];
    cp[0] = make_float4(c[0], c[1], c[2], c[3]);
    cp[1] = make_float4(c[4], c[5], c[6], c[7]);
    float4* op = (float4*)&o_preT[(size_t)n * BATCH];
    op[0] = make_float4(o[0], o[1], o[2], o[3]);
    op[1] = make_float4(o[4], o[5], o[6], o[7]);
    float4* ep = (float4*)&E_T[(size_t)n * BATCH];
    ep[0] = make_float4(ee[0], ee[1], ee[2], ee[3]);
    ep[1] = make_float4(ee[4], ee[5], ee[6], ee[7]);
}
__global__ void edge_scatter_eb(const int* __restrict__ src,
                                const int* __restrict__ dst,
                                const float* __restrict__ w,
                                const float* __restrict__ o_preT,
                                const float* __restrict__ E_T,
                                float* __restrict__ chemT,
                                int edges) {
    int t = blockIdx.x * blockDim.x + threadIdx.x;
    int e = t >> 3;
    int b = t & 7;
    if (e >= edges) return;
    int s = src[e]; int d = dst[e]; float we = w[e];
    float Oj = o_preT[(size_t)s * BATCH + b];
    float En = E_T[(size_t)d * BATCH + b];
    float diff = Oj - En;
    float sg = (diff > 0.0f) ? 1.0f : ((diff < 0.0f) ? -1.0f : 0.0f);
    atomicAdd(&chemT[(size_t)d * BATCH + b], Oj * we * sg);
}
__global__ void finalize_nb(const float* __restrict__ E,
                            const float* __restrict__ chemT,
                            const float* __restrict__ thr,
                            const float* __restrict__ decay,
                            float* __restrict__ new_o,
                            float* __restrict__ new_e, int N) {
    int n = blockIdx.x * blockDim.x + threadIdx.x;
    if (n >= N) return;
    const float4* cp = (const float4*)&chemT[(size_t)n * BATCH];
    float4 c0 = cp[0], c1 = cp[1];
    float c[BATCH] = {c0.x, c0.y, c0.z, c0.w, c1.x, c1.y, c1.z, c1.w};
    float t = thr[n];
    float dc = decay[n];
    #pragma unroll
    for (int b = 0; b < BATCH; ++b) {
        int i = b * N + n;
        float e = E[i];
        float S = fminf(fmaxf(e + c[b], CLAMP_MIN_F), CLAMP_MAX_F);
        bool gt = S > t;
        float no = fmaxf(S - t, 0.0f);
        float ne = gt ? no : ((S == e) ? (e - dc) : S);
        new_o[i] = no;
        new_e[i] = ne;
    }
}

static inline size_t align256(size_t x) { return (x + 255) & ~(size_t)255; }

extern "C" void kernel_launch(void* const* d_in, const int* in_sizes, int n_in,
                              void* d_out, int out_size, void* d_ws, size_t ws_size,
                              hipStream_t stream) {
    const float* chem_influence = (const float*)d_in[0];
    const float* E              = (const float*)d_in[1];
    const int*   src            = (const int*)d_in[3];
    const int*   dst            = (const int*)d_in[4];
    const float* w              = (const float*)d_in[5];
    const float* o_pre          = (const float*)d_in[6];
    const float* threshold      = (const float*)d_in[7];
    const float* decay          = (const float*)d_in[8];

    const int edges = in_sizes[3];
    const int BN    = in_sizes[0];   // B * N
    const int N     = in_sizes[7];   // threshold is (N,)

    float* new_o = (float*)d_out;
    float* new_e = (float*)d_out + BN;

    const int TB = 256;
    int nblk = (N + TB - 1) / TB;

    const int K    = (N + RNODES - 1) >> R_LOG;        // buckets (64 nodes)
    const int KPAD = (K + 31) & ~31;
    const int NB   = (edges + EPB - 1) / EPB;          // binning blocks

    // ws layout
    size_t off = 0;
    size_t opreT_off  = off; off += align256((size_t)BN * 4);
    size_t ET_off     = off; off += align256((size_t)BN * 4);
    size_t base_off   = off; off += align256((size_t)(MAX2K + 1) * 4);
    size_t colsum_off = off; off += align256((size_t)MAX2K * 4);
    size_t hist_off   = off; off += align256((size_t)NB * KPAD * 4);
    size_t offs_off   = off; off += align256((size_t)NB * KPAD * 4);
    size_t rec_off    = off; off += align256((size_t)edges * 8);
    size_t need = off;

    char* wsb = (char*)d_ws;

    if (K <= MAX2K - 1 && ws_size >= need) {
        float*    o_preT = (float*)(wsb + opreT_off);
        float*    E_T    = (float*)(wsb + ET_off);
        unsigned* base   = (unsigned*)(wsb + base_off);
        unsigned* colSum = (unsigned*)(wsb + colsum_off);
        unsigned* hist   = (unsigned*)(wsb + hist_off);
        unsigned* offs   = (unsigned*)(wsb + offs_off);
        int2*     recS   = (int2*)(wsb + rec_off);

        prep2_kernel<<<nblk, TB, 0, stream>>>(o_pre, E, o_preT, E_T, N);
        hist_kernel<<<NB, TB, 0, stream>>>(dst, hist, edges, KPAD);
        colsum_kernel<<<(KPAD + TB - 1) / TB, TB, 0, stream>>>(hist, colSum, NB, KPAD);
        scan2_kernel<<<1, 1024, 0, stream>>>(colSum, base, KPAD);
        offs_kernel<<<(KPAD + TB - 1) / TB, TB, 0, stream>>>(hist, base, offs, NB, KPAD);
        scatter_kernel<<<NB, TB, 0, stream>>>(src, dst, w, offs, recS, edges, KPAD);
        accum_kernel<<<K, TB, 0, stream>>>(recS, base, o_preT, E_T,
                                           chem_influence, threshold, decay,
                                           new_o, new_e, N);
    } else if (ws_size >= 3 * (size_t)BN * 4) {
        float* chemT  = (float*)d_ws;
        float* o_preT = chemT + BN;
        float* E_T    = o_preT + BN;
        prep_kernel<<<nblk, TB, 0, stream>>>(chem_influence, o_pre, E,
                                             chemT, o_preT, E_T, N);
        long long ethreads = (long long)edges * BATCH;
        int gblk = (int)((ethreads + TB - 1) / TB);
        edge_scatter_eb<<<gblk, TB, 0, stream>>>(src, dst, w, o_preT, E_T,
                                                 chemT, edges);
        finalize_nb<<<nblk, TB, 0, stream>>>(E, chemT, threshold, decay,
                                             new_o, new_e, N);
    }
}

// Round 7
// 323.046 us; speedup vs baseline: 1.1407x; 1.0941x over previous
//
#include <hip/hip_runtime.h>

#define CLAMP_MIN_F (-10.0f)
#define CLAMP_MAX_F (10.0f)
#define BATCH 8
#define R_LOG 6          // 64 nodes per bucket
#define RNODES 64
#define EPB 8192         // edges per binning block
#define MAX2K 2048       // scan capacity (K must be <= 2047)
#define ASTR 9           // LDS row stride (pad 8 -> 9)

// ---------------- prep: transpose o_pre (B,N) -> (N,B) ----------------------
__global__ void prep_o_kernel(const float* __restrict__ o_pre,
                              float* __restrict__ o_preT,
                              int N) {
    int n = blockIdx.x * blockDim.x + threadIdx.x;
    if (n >= N) return;
    float o[BATCH];
    #pragma unroll
    for (int b = 0; b < BATCH; ++b) o[b] = o_pre[b * N + n];
    float4* op = (float4*)&o_preT[(size_t)n * BATCH];
    op[0] = make_float4(o[0], o[1], o[2], o[3]);
    op[1] = make_float4(o[4], o[5], o[6], o[7]);
}

// ---------------- pass 1: per-block histogram over buckets ------------------
__global__ void hist_kernel(const int* __restrict__ dst,
                            unsigned* __restrict__ hist,
                            int edges, int KPAD) {
    __shared__ unsigned sh[MAX2K];
    int bid = blockIdx.x;
    for (int k = threadIdx.x; k < KPAD; k += blockDim.x) sh[k] = 0u;
    __syncthreads();
    int start = bid * EPB;
    int end = min(edges, start + EPB);
    for (int i = start + threadIdx.x; i < end; i += blockDim.x)
        atomicAdd(&sh[((unsigned)dst[i]) >> R_LOG], 1u);
    __syncthreads();
    for (int k = threadIdx.x; k < KPAD; k += blockDim.x)
        hist[(size_t)bid * KPAD + k] = sh[k];
}

// ------- pass 2a: per-column exclusive prefix over blocks + column totals ---
// thread-per-column; all loads/stores coalesced (row-major hist).
__global__ void colprefix_kernel(const unsigned* __restrict__ hist,
                                 unsigned* __restrict__ offs0,
                                 unsigned* __restrict__ total,
                                 int NB, int KPAD) {
    int k = blockIdx.x * blockDim.x + threadIdx.x;
    if (k >= KPAD) return;
    unsigned run = 0;
    for (int b = 0; b < NB; ++b) {
        unsigned v = hist[(size_t)b * KPAD + k];
        offs0[(size_t)b * KPAD + k] = run;
        run += v;
    }
    total[k] = run;
}

// ---------------- pass 2b: exclusive scan over bucket totals (<=2048) -------
__global__ void scan2_kernel(const unsigned* __restrict__ total,
                             unsigned* __restrict__ base,
                             int KPAD) {
    __shared__ unsigned s1[1024];
    __shared__ unsigned s2[1024];
    int t = threadIdx.x;
    unsigned a = (2 * t     < KPAD) ? total[2 * t]     : 0u;
    unsigned b = (2 * t + 1 < KPAD) ? total[2 * t + 1] : 0u;
    s1[t] = a + b;
    __syncthreads();
    unsigned* cur = s1;
    unsigned* nxt = s2;
    for (int off = 1; off < 1024; off <<= 1) {
        unsigned v = cur[t];
        if (t >= off) v += cur[t - off];
        nxt[t] = v;
        __syncthreads();
        unsigned* tmp = cur; cur = nxt; nxt = tmp;
    }
    unsigned incl = cur[t];
    unsigned excl = incl - (a + b);
    base[2 * t]     = excl;
    base[2 * t + 1] = excl + a;
    if (t == 1023) base[2048] = incl;
}

// ---------------- pass 3: scatter edges into 8B bucket-sorted records -------
// key = (dst_local:6 bits << 26) | src   (src < 2^26)
__global__ void scatter_kernel(const int* __restrict__ src,
                               const int* __restrict__ dst,
                               const float* __restrict__ w,
                               const unsigned* __restrict__ offs0,
                               const unsigned* __restrict__ base,
                               int2* __restrict__ recS,
                               int edges, int KPAD) {
    __shared__ unsigned loffs[MAX2K];
    int bid = blockIdx.x;
    for (int k = threadIdx.x; k < KPAD; k += blockDim.x)
        loffs[k] = base[k] + offs0[(size_t)bid * KPAD + k];
    __syncthreads();
    int start = bid * EPB;
    int end = min(edges, start + EPB);
    for (int i = start + threadIdx.x; i < end; i += blockDim.x) {
        int d = dst[i];
        int s = src[i];
        float wv = w[i];
        unsigned k = ((unsigned)d) >> R_LOG;
        unsigned pos = atomicAdd(&loffs[k], 1u);
        unsigned key = (((unsigned)d & (RNODES - 1)) << 26) | (unsigned)s;
        recS[pos] = make_int2((int)key, __float_as_int(wv));
    }
}

// ------- pass 4: per-bucket accumulate + fused finalize ---------------------
// Thread-per-record: each lane issues its OWN random 32B o_preT gather
// (64 lines in flight per wave-load -> 8x the MLP of group-per-record).
// E for the bucket's 64 nodes is staged in LDS (kills the E gather stream).
__global__ void accum_kernel(const int2* __restrict__ recS,
                             const unsigned* __restrict__ base,
                             const float* __restrict__ o_preT,   // (N,B)
                             const float* __restrict__ E,        // (B,N)
                             const float* __restrict__ chem_in,  // (B,N)
                             const float* __restrict__ thr,
                             const float* __restrict__ decay,
                             float* __restrict__ new_o,          // (B,N)
                             float* __restrict__ new_e,          // (B,N)
                             int N) {
    __shared__ float acc[RNODES * ASTR];
    __shared__ float e_lds[RNODES * ASTR];
    int k = blockIdx.x;
    int ns = k << R_LOG;
    int cnt = min(RNODES, N - ns);
    // zero acc
    for (int i = threadIdx.x; i < RNODES * ASTR; i += blockDim.x) acc[i] = 0.f;
    // stage E[b][ns..ns+cnt) into e_lds[n*ASTR+b] (coalesced global reads)
    for (int i = threadIdx.x; i < RNODES * BATCH; i += blockDim.x) {
        int b = i >> R_LOG;        // 0..7
        int n = i & (RNODES - 1);  // 0..63
        if (n < cnt) e_lds[n * ASTR + b] = E[(size_t)b * N + ns + n];
    }
    __syncthreads();

    unsigned b0 = base[k], b1 = base[k + 1];
    unsigned r = b0 + threadIdx.x;
    // 2-way unrolled thread-per-record loop
    for (; r + blockDim.x < b1; r += 2u * blockDim.x) {
        int2 rec0 = recS[r];
        int2 rec1 = recS[r + blockDim.x];
        unsigned k0 = (unsigned)rec0.x, k1 = (unsigned)rec1.x;
        const float4* p0 = (const float4*)&o_preT[(size_t)(k0 & 0x3FFFFFFu) << 3];
        const float4* p1 = (const float4*)&o_preT[(size_t)(k1 & 0x3FFFFFFu) << 3];
        float4 a0 = p0[0], a1 = p0[1];
        float4 c0 = p1[0], c1 = p1[1];
        int dl0 = (int)(k0 >> 26), dl1 = (int)(k1 >> 26);
        float w0 = __int_as_float(rec0.y), w1 = __int_as_float(rec1.y);
        float Oj0[BATCH] = {a0.x,a0.y,a0.z,a0.w,a1.x,a1.y,a1.z,a1.w};
        float Oj1[BATCH] = {c0.x,c0.y,c0.z,c0.w,c1.x,c1.y,c1.z,c1.w};
        #pragma unroll
        for (int j = 0; j < BATCH; ++j) {
            float En = e_lds[dl0 * ASTR + j];
            float d = Oj0[j] - En;
            float sg = (d > 0.f) ? 1.f : ((d < 0.f) ? -1.f : 0.f);
            atomicAdd(&acc[dl0 * ASTR + j], Oj0[j] * w0 * sg);
        }
        #pragma unroll
        for (int j = 0; j < BATCH; ++j) {
            float En = e_lds[dl1 * ASTR + j];
            float d = Oj1[j] - En;
            float sg = (d > 0.f) ? 1.f : ((d < 0.f) ? -1.f : 0.f);
            atomicAdd(&acc[dl1 * ASTR + j], Oj1[j] * w1 * sg);
        }
    }
    if (r < b1) {
        int2 rec = recS[r];
        unsigned kk = (unsigned)rec.x;
        const float4* p = (const float4*)&o_preT[(size_t)(kk & 0x3FFFFFFu) << 3];
        float4 a0 = p[0], a1 = p[1];
        int dl = (int)(kk >> 26);
        float wv = __int_as_float(rec.y);
        float Oj[BATCH] = {a0.x,a0.y,a0.z,a0.w,a1.x,a1.y,a1.z,a1.w};
        #pragma unroll
        for (int j = 0; j < BATCH; ++j) {
            float En = e_lds[dl * ASTR + j];
            float d = Oj[j] - En;
            float sg = (d > 0.f) ? 1.f : ((d < 0.f) ? -1.f : 0.f);
            atomicAdd(&acc[dl * ASTR + j], Oj[j] * wv * sg);
        }
    }
    __syncthreads();

    // fused finalize: iterate [batch][node] so global IO is coalesced
    for (int i = threadIdx.x; i < RNODES * BATCH; i += blockDim.x) {
        int b = i >> R_LOG;
        int n = i & (RNODES - 1);
        if (n >= cnt) continue;
        float e = e_lds[n * ASTR + b];
        float S = e + chem_in[(size_t)b * N + ns + n] + acc[n * ASTR + b];
        S = fminf(fmaxf(S, CLAMP_MIN_F), CLAMP_MAX_F);
        float t  = thr[ns + n];
        float dc = decay[ns + n];
        bool gt = S > t;
        float no = fmaxf(S - t, 0.f);
        float ne = gt ? no : ((S == e) ? (e - dc) : S);
        new_o[(size_t)b * N + ns + n] = no;
        new_e[(size_t)b * N + ns + n] = ne;
    }
}

// ---------------- fallback: R3 atomic path ----------------------------------
__global__ void prep_kernel(const float* __restrict__ chem_in,
                            const float* __restrict__ o_pre,
                            const float* __restrict__ E,
                            float* __restrict__ chemT,
                            float* __restrict__ o_preT,
                            float* __restrict__ E_T,
                            int N) {
    int n = blockIdx.x * blockDim.x + threadIdx.x;
    if (n >= N) return;
    float c[BATCH], o[BATCH], ee[BATCH];
    #pragma unroll
    for (int b = 0; b < BATCH; ++b) {
        c[b]  = chem_in[b * N + n];
        o[b]  = o_pre[b * N + n];
        ee[b] = E[b * N + n];
    }
    float4* cp = (float4*)&chemT[(size_t)n * BATCH];
    cp[0] = make_float4(c[0], c[1], c[2], c[3]);
    cp[1] = make_float4(c[4], c[5], c[6], c[7]);
    float4* op = (float4*)&o_preT[(size_t)n * BATCH];
    op[0] = make_float4(o[0], o[1], o[2], o[3]);
    op[1] = make_float4(o[4], o[5], o[6], o[7]);
    float4* ep = (float4*)&E_T[(size_t)n * BATCH];
    ep[0] = make_float4(ee[0], ee[1], ee[2], ee[3]);
    ep[1] = make_float4(ee[4], ee[5], ee[6], ee[7]);
}
__global__ void edge_scatter_eb(const int* __restrict__ src,
                                const int* __restrict__ dst,
                                const float* __restrict__ w,
                                const float* __restrict__ o_preT,
                                const float* __restrict__ E_T,
                                float* __restrict__ chemT,
                                int edges) {
    int t = blockIdx.x * blockDim.x + threadIdx.x;
    int e = t >> 3;
    int b = t & 7;
    if (e >= edges) return;
    int s = src[e]; int d = dst[e]; float we = w[e];
    float Oj = o_preT[(size_t)s * BATCH + b];
    float En = E_T[(size_t)d * BATCH + b];
    float diff = Oj - En;
    float sg = (diff > 0.0f) ? 1.0f : ((diff < 0.0f) ? -1.0f : 0.0f);
    atomicAdd(&chemT[(size_t)d * BATCH + b], Oj * we * sg);
}
__global__ void finalize_nb(const float* __restrict__ E,
                            const float* __restrict__ chemT,
                            const float* __restrict__ thr,
                            const float* __restrict__ decay,
                            float* __restrict__ new_o,
                            float* __restrict__ new_e, int N) {
    int n = blockIdx.x * blockDim.x + threadIdx.x;
    if (n >= N) return;
    const float4* cp = (const float4*)&chemT[(size_t)n * BATCH];
    float4 c0 = cp[0], c1 = cp[1];
    float c[BATCH] = {c0.x, c0.y, c0.z, c0.w, c1.x, c1.y, c1.z, c1.w};
    float t = thr[n];
    float dc = decay[n];
    #pragma unroll
    for (int b = 0; b < BATCH; ++b) {
        int i = b * N + n;
        float e = E[i];
        float S = fminf(fmaxf(e + c[b], CLAMP_MIN_F), CLAMP_MAX_F);
        bool gt = S > t;
        float no = fmaxf(S - t, 0.0f);
        float ne = gt ? no : ((S == e) ? (e - dc) : S);
        new_o[i] = no;
        new_e[i] = ne;
    }
}

static inline size_t align256(size_t x) { return (x + 255) & ~(size_t)255; }

extern "C" void kernel_launch(void* const* d_in, const int* in_sizes, int n_in,
                              void* d_out, int out_size, void* d_ws, size_t ws_size,
                              hipStream_t stream) {
    const float* chem_influence = (const float*)d_in[0];
    const float* E              = (const float*)d_in[1];
    const int*   src            = (const int*)d_in[3];
    const int*   dst            = (const int*)d_in[4];
    const float* w              = (const float*)d_in[5];
    const float* o_pre          = (const float*)d_in[6];
    const float* threshold      = (const float*)d_in[7];
    const float* decay          = (const float*)d_in[8];

    const int edges = in_sizes[3];
    const int BN    = in_sizes[0];   // B * N
    const int N     = in_sizes[7];   // threshold is (N,)

    float* new_o = (float*)d_out;
    float* new_e = (float*)d_out + BN;

    const int TB = 256;
    int nblk = (N + TB - 1) / TB;

    const int K    = (N + RNODES - 1) >> R_LOG;        // buckets (64 nodes)
    const int KPAD = (K + 63) & ~63;
    const int NB   = (edges + EPB - 1) / EPB;          // binning blocks

    // ws layout
    size_t off = 0;
    size_t opreT_off  = off; off += align256((size_t)BN * 4);
    size_t base_off   = off; off += align256((size_t)(MAX2K + 1) * 4);
    size_t total_off  = off; off += align256((size_t)MAX2K * 4);
    size_t hist_off   = off; off += align256((size_t)NB * KPAD * 4);
    size_t offs0_off  = off; off += align256((size_t)NB * KPAD * 4);
    size_t rec_off    = off; off += align256((size_t)edges * 8);
    size_t need = off;

    char* wsb = (char*)d_ws;

    if (K <= MAX2K - 1 && ws_size >= need) {
        float*    o_preT = (float*)(wsb + opreT_off);
        unsigned* base   = (unsigned*)(wsb + base_off);
        unsigned* total  = (unsigned*)(wsb + total_off);
        unsigned* hist   = (unsigned*)(wsb + hist_off);
        unsigned* offs0  = (unsigned*)(wsb + offs0_off);
        int2*     recS   = (int2*)(wsb + rec_off);

        prep_o_kernel<<<nblk, TB, 0, stream>>>(o_pre, o_preT, N);
        hist_kernel<<<NB, TB, 0, stream>>>(dst, hist, edges, KPAD);
        colprefix_kernel<<<(KPAD + TB - 1) / TB, TB, 0, stream>>>(hist, offs0, total, NB, KPAD);
        scan2_kernel<<<1, 1024, 0, stream>>>(total, base, KPAD);
        scatter_kernel<<<NB, TB, 0, stream>>>(src, dst, w, offs0, base, recS, edges, KPAD);
        accum_kernel<<<K, TB, 0, stream>>>(recS, base, o_preT, E,
                                           chem_influence, threshold, decay,
                                           new_o, new_e, N);
    } else if (ws_size >= 3 * (size_t)BN * 4) {
        float* chemT  = (float*)d_ws;
        float* o_preT = chemT + BN;
        float* E_T    = o_preT + BN;
        prep_kernel<<<nblk, TB, 0, stream>>>(chem_influence, o_pre, E,
                                             chemT, o_preT, E_T, N);
        long long ethreads = (long long)edges * BATCH;
        int gblk = (int)((ethreads + TB - 1) / TB);
        edge_scatter_eb<<<gblk, TB, 0, stream>>>(src, dst, w, o_preT, E_T,
                                                 chemT, edges);
        finalize_nb<<<nblk, TB, 0, stream>>>(E, chemT, threshold, decay,
                                             new_o, new_e, N);
    }
}

// Round 8
// 223.400 us; speedup vs baseline: 1.6494x; 1.4460x over previous
//
#include <hip/hip_runtime.h>

#define CLAMP_MIN_F (-10.0f)
#define CLAMP_MAX_F (10.0f)
#define BATCH 8
#define R_LOG 5          // 32 nodes per bucket
#define RNODES 32
#define ASTR 9           // LDS row stride (pad 8 -> 9)
#define EPB 16384        // edges per binning block
#define TB_BIN 1024      // threads for hist/scatter
#define MAX4K 4096       // scan capacity (K must be <= 4095)

// ---- prep: transpose o_pre (B,N) -> (N,B); zero bucket totals --------------
__global__ void prep_o_kernel(const float* __restrict__ o_pre,
                              float* __restrict__ o_preT,
                              unsigned* __restrict__ total,
                              int N) {
    int n = blockIdx.x * blockDim.x + threadIdx.x;
    if (n < MAX4K) total[n] = 0u;
    if (n >= N) return;
    float o[BATCH];
    #pragma unroll
    for (int b = 0; b < BATCH; ++b) o[b] = o_pre[b * N + n];
    float4* op = (float4*)&o_preT[(size_t)n * BATCH];
    op[0] = make_float4(o[0], o[1], o[2], o[3]);
    op[1] = make_float4(o[4], o[5], o[6], o[7]);
}

// ---- pass 1: per-block histogram + direct space reservation ----------------
// offs0[bid][k] = this block's starting slot within bucket k (atomic-return).
__global__ void hist_reserve_kernel(const int* __restrict__ dst,
                                    unsigned* __restrict__ total,
                                    unsigned* __restrict__ offs0,
                                    int edges, int KPAD) {
    __shared__ unsigned sh[MAX4K];
    int bid = blockIdx.x;
    for (int k = threadIdx.x; k < KPAD; k += blockDim.x) sh[k] = 0u;
    __syncthreads();
    int start = bid * EPB;
    int end = min(edges, start + EPB);
    for (int i = start + threadIdx.x; i < end; i += blockDim.x)
        atomicAdd(&sh[((unsigned)dst[i]) >> R_LOG], 1u);
    __syncthreads();
    for (int k = threadIdx.x; k < KPAD; k += blockDim.x) {
        unsigned c = sh[k];
        offs0[(size_t)bid * KPAD + k] = c ? atomicAdd(&total[k], c) : 0u;
    }
}

// ---- pass 2: exclusive scan over bucket totals (<=4096), 1024 thr x 4 ------
__global__ void scan4_kernel(const unsigned* __restrict__ total,
                             unsigned* __restrict__ base,
                             int KPAD) {
    __shared__ unsigned s1[1024];
    __shared__ unsigned s2[1024];
    int t = threadIdx.x;
    unsigned v0 = (4 * t     < KPAD) ? total[4 * t]     : 0u;
    unsigned v1 = (4 * t + 1 < KPAD) ? total[4 * t + 1] : 0u;
    unsigned v2 = (4 * t + 2 < KPAD) ? total[4 * t + 2] : 0u;
    unsigned v3 = (4 * t + 3 < KPAD) ? total[4 * t + 3] : 0u;
    unsigned sum = v0 + v1 + v2 + v3;
    s1[t] = sum;
    __syncthreads();
    unsigned* cur = s1;
    unsigned* nxt = s2;
    for (int off = 1; off < 1024; off <<= 1) {
        unsigned x = cur[t];
        if (t >= off) x += cur[t - off];
        nxt[t] = x;
        __syncthreads();
        unsigned* tmp = cur; cur = nxt; nxt = tmp;
    }
    unsigned incl = cur[t];
    unsigned excl = incl - sum;
    base[4 * t]     = excl;
    base[4 * t + 1] = excl + v0;
    base[4 * t + 2] = excl + v0 + v1;
    base[4 * t + 3] = excl + v0 + v1 + v2;
    if (t == 1023) base[4096] = incl;
}

// ---- pass 3: scatter edges into 8B bucket-sorted records -------------------
// key = (dst_local:5 bits << 26) | src   (src < 2^26)
__global__ void scatter_kernel(const int* __restrict__ src,
                               const int* __restrict__ dst,
                               const float* __restrict__ w,
                               const unsigned* __restrict__ offs0,
                               const unsigned* __restrict__ base,
                               int2* __restrict__ recS,
                               int edges, int KPAD) {
    __shared__ unsigned loffs[MAX4K];
    int bid = blockIdx.x;
    for (int k = threadIdx.x; k < KPAD; k += blockDim.x)
        loffs[k] = base[k] + offs0[(size_t)bid * KPAD + k];
    __syncthreads();
    int start = bid * EPB;
    int end = min(edges, start + EPB);
    for (int i = start + threadIdx.x; i < end; i += blockDim.x) {
        int d = dst[i];
        int s = src[i];
        float wv = w[i];
        unsigned k = ((unsigned)d) >> R_LOG;
        unsigned pos = atomicAdd(&loffs[k], 1u);
        unsigned key = (((unsigned)d & (RNODES - 1)) << 26) | (unsigned)s;
        recS[pos] = make_int2((int)key, __float_as_int(wv));
    }
}

// ---- pass 4: per-bucket accumulate + fused finalize -------------------------
// Thread-per-record, 4 independent record->gather chains per thread.
// Dummy records (w=0) make the tail guard-free: contrib is exactly 0.
__global__ void accum_kernel(const int2* __restrict__ recS,
                             const unsigned* __restrict__ base,
                             const float* __restrict__ o_preT,   // (N,B)
                             const float* __restrict__ E,        // (B,N)
                             const float* __restrict__ chem_in,  // (B,N)
                             const float* __restrict__ thr,
                             const float* __restrict__ decay,
                             float* __restrict__ new_o,          // (B,N)
                             float* __restrict__ new_e,          // (B,N)
                             int N) {
    __shared__ float acc[RNODES * ASTR];
    __shared__ float e_lds[RNODES * ASTR];
    int k = blockIdx.x;
    int ns = k << R_LOG;
    int cnt = min(RNODES, N - ns);
    for (int i = threadIdx.x; i < RNODES * ASTR; i += blockDim.x) acc[i] = 0.f;
    for (int i = threadIdx.x; i < RNODES * BATCH; i += blockDim.x) {
        int b = i >> R_LOG;
        int n = i & (RNODES - 1);
        if (n < cnt) e_lds[n * ASTR + b] = E[(size_t)b * N + ns + n];
    }
    __syncthreads();

    unsigned b0 = base[k], b1 = base[k + 1];
    unsigned stride = blockDim.x;
    for (unsigned r0 = b0 + threadIdx.x; r0 < b1; r0 += 4u * stride) {
        unsigned r1 = r0 + stride, r2 = r0 + 2u * stride, r3 = r0 + 3u * stride;
        // guarded record loads; dummies carry w=0 -> zero contribution
        int2 rec0 = recS[r0];
        int2 rec1 = (r1 < b1) ? recS[r1] : make_int2(0, 0);
        int2 rec2 = (r2 < b1) ? recS[r2] : make_int2(0, 0);
        int2 rec3 = (r3 < b1) ? recS[r3] : make_int2(0, 0);
        // 4 independent random gathers (issue together, wait together)
        const float4* p0 = (const float4*)&o_preT[(size_t)((unsigned)rec0.x & 0x3FFFFFFu) << 3];
        const float4* p1 = (const float4*)&o_preT[(size_t)((unsigned)rec1.x & 0x3FFFFFFu) << 3];
        const float4* p2 = (const float4*)&o_preT[(size_t)((unsigned)rec2.x & 0x3FFFFFFu) << 3];
        const float4* p3 = (const float4*)&o_preT[(size_t)((unsigned)rec3.x & 0x3FFFFFFu) << 3];
        float4 a0 = p0[0], a1 = p0[1];
        float4 b0v = p1[0], b1v = p1[1];
        float4 c0 = p2[0], c1 = p2[1];
        float4 d0 = p3[0], d1 = p3[1];
        int dl0 = (int)(((unsigned)rec0.x >> 26) & (RNODES - 1));
        int dl1 = (int)(((unsigned)rec1.x >> 26) & (RNODES - 1));
        int dl2 = (int)(((unsigned)rec2.x >> 26) & (RNODES - 1));
        int dl3 = (int)(((unsigned)rec3.x >> 26) & (RNODES - 1));
        float w0 = __int_as_float(rec0.y);
        float w1 = __int_as_float(rec1.y);
        float w2 = __int_as_float(rec2.y);
        float w3 = __int_as_float(rec3.y);
        float Oj0[BATCH] = {a0.x,a0.y,a0.z,a0.w,a1.x,a1.y,a1.z,a1.w};
        float Oj1[BATCH] = {b0v.x,b0v.y,b0v.z,b0v.w,b1v.x,b1v.y,b1v.z,b1v.w};
        float Oj2[BATCH] = {c0.x,c0.y,c0.z,c0.w,c1.x,c1.y,c1.z,c1.w};
        float Oj3[BATCH] = {d0.x,d0.y,d0.z,d0.w,d1.x,d1.y,d1.z,d1.w};
        #pragma unroll
        for (int j = 0; j < BATCH; ++j) {
            float En = e_lds[dl0 * ASTR + j];
            float df = Oj0[j] - En;
            float sg = (df > 0.f) ? 1.f : ((df < 0.f) ? -1.f : 0.f);
            atomicAdd(&acc[dl0 * ASTR + j], Oj0[j] * w0 * sg);
        }
        #pragma unroll
        for (int j = 0; j < BATCH; ++j) {
            float En = e_lds[dl1 * ASTR + j];
            float df = Oj1[j] - En;
            float sg = (df > 0.f) ? 1.f : ((df < 0.f) ? -1.f : 0.f);
            atomicAdd(&acc[dl1 * ASTR + j], Oj1[j] * w1 * sg);
        }
        #pragma unroll
        for (int j = 0; j < BATCH; ++j) {
            float En = e_lds[dl2 * ASTR + j];
            float df = Oj2[j] - En;
            float sg = (df > 0.f) ? 1.f : ((df < 0.f) ? -1.f : 0.f);
            atomicAdd(&acc[dl2 * ASTR + j], Oj2[j] * w2 * sg);
        }
        #pragma unroll
        for (int j = 0; j < BATCH; ++j) {
            float En = e_lds[dl3 * ASTR + j];
            float df = Oj3[j] - En;
            float sg = (df > 0.f) ? 1.f : ((df < 0.f) ? -1.f : 0.f);
            atomicAdd(&acc[dl3 * ASTR + j], Oj3[j] * w3 * sg);
        }
    }
    __syncthreads();

    // fused finalize: 32 nodes x 8 batches = 256 elems, one per thread
    for (int i = threadIdx.x; i < RNODES * BATCH; i += blockDim.x) {
        int b = i >> R_LOG;
        int n = i & (RNODES - 1);
        if (n >= cnt) continue;
        float e = e_lds[n * ASTR + b];
        float S = e + chem_in[(size_t)b * N + ns + n] + acc[n * ASTR + b];
        S = fminf(fmaxf(S, CLAMP_MIN_F), CLAMP_MAX_F);
        float t  = thr[ns + n];
        float dc = decay[ns + n];
        bool gt = S > t;
        float no = fmaxf(S - t, 0.f);
        float ne = gt ? no : ((S == e) ? (e - dc) : S);
        new_o[(size_t)b * N + ns + n] = no;
        new_e[(size_t)b * N + ns + n] = ne;
    }
}

// ---------------- fallback: R3 atomic path ----------------------------------
__global__ void prep_kernel(const float* __restrict__ chem_in,
                            const float* __restrict__ o_pre,
                            const float* __restrict__ E,
                            float* __restrict__ chemT,
                            float* __restrict__ o_preT,
                            float* __restrict__ E_T,
                            int N) {
    int n = blockIdx.x * blockDim.x + threadIdx.x;
    if (n >= N) return;
    float c[BATCH], o[BATCH], ee[BATCH];
    #pragma unroll
    for (int b = 0; b < BATCH; ++b) {
        c[b]  = chem_in[b * N + n];
        o[b]  = o_pre[b * N + n];
        ee[b] = E[b * N + n];
    }
    float4* cp = (float4*)&chemT[(size_t)n * BATCH];
    cp[0] = make_float4(c[0], c[1], c[2], c[3]);
    cp[1] = make_float4(c[4], c[5], c[6], c[7]);
    float4* op = (float4*)&o_preT[(size_t)n * BATCH];
    op[0] = make_float4(o[0], o[1], o[2], o[3]);
    op[1] = make_float4(o[4], o[5], o[6], o[7]);
    float4* ep = (float4*)&E_T[(size_t)n * BATCH];
    ep[0] = make_float4(ee[0], ee[1], ee[2], ee[3]);
    ep[1] = make_float4(ee[4], ee[5], ee[6], ee[7]);
}
__global__ void edge_scatter_eb(const int* __restrict__ src,
                                const int* __restrict__ dst,
                                const float* __restrict__ w,
                                const float* __restrict__ o_preT,
                                const float* __restrict__ E_T,
                                float* __restrict__ chemT,
                                int edges) {
    int t = blockIdx.x * blockDim.x + threadIdx.x;
    int e = t >> 3;
    int b = t & 7;
    if (e >= edges) return;
    int s = src[e]; int d = dst[e]; float we = w[e];
    float Oj = o_preT[(size_t)s * BATCH + b];
    float En = E_T[(size_t)d * BATCH + b];
    float diff = Oj - En;
    float sg = (diff > 0.0f) ? 1.0f : ((diff < 0.0f) ? -1.0f : 0.0f);
    atomicAdd(&chemT[(size_t)d * BATCH + b], Oj * we * sg);
}
__global__ void finalize_nb(const float* __restrict__ E,
                            const float* __restrict__ chemT,
                            const float* __restrict__ thr,
                            const float* __restrict__ decay,
                            float* __restrict__ new_o,
                            float* __restrict__ new_e, int N) {
    int n = blockIdx.x * blockDim.x + threadIdx.x;
    if (n >= N) return;
    const float4* cp = (const float4*)&chemT[(size_t)n * BATCH];
    float4 c0 = cp[0], c1 = cp[1];
    float c[BATCH] = {c0.x, c0.y, c0.z, c0.w, c1.x, c1.y, c1.z, c1.w};
    float t = thr[n];
    float dc = decay[n];
    #pragma unroll
    for (int b = 0; b < BATCH; ++b) {
        int i = b * N + n;
        float e = E[i];
        float S = fminf(fmaxf(e + c[b], CLAMP_MIN_F), CLAMP_MAX_F);
        bool gt = S > t;
        float no = fmaxf(S - t, 0.0f);
        float ne = gt ? no : ((S == e) ? (e - dc) : S);
        new_o[i] = no;
        new_e[i] = ne;
    }
}

static inline size_t align256(size_t x) { return (x + 255) & ~(size_t)255; }

extern "C" void kernel_launch(void* const* d_in, const int* in_sizes, int n_in,
                              void* d_out, int out_size, void* d_ws, size_t ws_size,
                              hipStream_t stream) {
    const float* chem_influence = (const float*)d_in[0];
    const float* E              = (const float*)d_in[1];
    const int*   src            = (const int*)d_in[3];
    const int*   dst            = (const int*)d_in[4];
    const float* w              = (const float*)d_in[5];
    const float* o_pre          = (const float*)d_in[6];
    const float* threshold      = (const float*)d_in[7];
    const float* decay          = (const float*)d_in[8];

    const int edges = in_sizes[3];
    const int BN    = in_sizes[0];   // B * N
    const int N     = in_sizes[7];   // threshold is (N,)

    float* new_o = (float*)d_out;
    float* new_e = (float*)d_out + BN;

    const int TB = 256;
    int nblk = (N + TB - 1) / TB;

    const int K    = (N + RNODES - 1) >> R_LOG;        // buckets (32 nodes)
    const int KPAD = (K + 63) & ~63;
    const int NB   = (edges + EPB - 1) / EPB;          // binning blocks

    // ws layout
    size_t off = 0;
    size_t opreT_off  = off; off += align256((size_t)BN * 4);
    size_t base_off   = off; off += align256((size_t)(MAX4K + 1) * 4);
    size_t total_off  = off; off += align256((size_t)MAX4K * 4);
    size_t offs0_off  = off; off += align256((size_t)NB * KPAD * 4);
    size_t rec_off    = off; off += align256((size_t)edges * 8);
    size_t need = off;

    char* wsb = (char*)d_ws;

    if (K <= MAX4K - 1 && ws_size >= need) {
        float*    o_preT = (float*)(wsb + opreT_off);
        unsigned* base   = (unsigned*)(wsb + base_off);
        unsigned* total  = (unsigned*)(wsb + total_off);
        unsigned* offs0  = (unsigned*)(wsb + offs0_off);
        int2*     recS   = (int2*)(wsb + rec_off);

        prep_o_kernel<<<nblk, TB, 0, stream>>>(o_pre, o_preT, total, N);
        hist_reserve_kernel<<<NB, TB_BIN, 0, stream>>>(dst, total, offs0, edges, KPAD);
        scan4_kernel<<<1, 1024, 0, stream>>>(total, base, KPAD);
        scatter_kernel<<<NB, TB_BIN, 0, stream>>>(src, dst, w, offs0, base, recS, edges, KPAD);
        accum_kernel<<<K, TB, 0, stream>>>(recS, base, o_preT, E,
                                           chem_influence, threshold, decay,
                                           new_o, new_e, N);
    } else if (ws_size >= 3 * (size_t)BN * 4) {
        float* chemT  = (float*)d_ws;
        float* o_preT = chemT + BN;
        float* E_T    = o_preT + BN;
        prep_kernel<<<nblk, TB, 0, stream>>>(chem_influence, o_pre, E,
                                             chemT, o_preT, E_T, N);
        long long ethreads = (long long)edges * BATCH;
        int gblk = (int)((ethreads + TB - 1) / TB);
        edge_scatter_eb<<<gblk, TB, 0, stream>>>(src, dst, w, o_preT, E_T,
                                                 chemT, edges);
        finalize_nb<<<nblk, TB, 0, stream>>>(E, chemT, threshold, decay,
                                             new_o, new_e, N);
    }
}

// Round 9
// 217.119 us; speedup vs baseline: 1.6972x; 1.0289x over previous
//
#include <hip/hip_runtime.h>

#define CLAMP_MIN_F (-10.0f)
#define CLAMP_MAX_F (10.0f)
#define BATCH 8
#define R_LOG 5          // 32 nodes per bucket
#define RNODES 32
#define ASTR 9           // LDS row stride (pad 8 -> 9)
#define EPB 16384        // edges per binning block
#define TB_BIN 1024      // threads for hist/scatter
#define MAX4K 4096       // scan capacity (K must be <= 4095)

// ---- prep: transpose o_pre (B,N) -> (N,B); zero bucket totals --------------
__global__ void prep_o_kernel(const float* __restrict__ o_pre,
                              float* __restrict__ o_preT,
                              unsigned* __restrict__ total,
                              int N) {
    int n = blockIdx.x * blockDim.x + threadIdx.x;
    if (n < MAX4K) total[n] = 0u;
    if (n >= N) return;
    float o[BATCH];
    #pragma unroll
    for (int b = 0; b < BATCH; ++b) o[b] = o_pre[b * N + n];
    float4* op = (float4*)&o_preT[(size_t)n * BATCH];
    op[0] = make_float4(o[0], o[1], o[2], o[3]);
    op[1] = make_float4(o[4], o[5], o[6], o[7]);
}

// ---- pass 1: per-block histogram + direct space reservation ----------------
__global__ void hist_reserve_kernel(const int* __restrict__ dst,
                                    unsigned* __restrict__ total,
                                    unsigned* __restrict__ offs0,
                                    int edges, int KPAD) {
    __shared__ unsigned sh[MAX4K];
    int bid = blockIdx.x;
    for (int k = threadIdx.x; k < KPAD; k += blockDim.x) sh[k] = 0u;
    __syncthreads();
    int start = bid * EPB;
    int end = min(edges, start + EPB);
    for (int i = start + threadIdx.x; i < end; i += blockDim.x)
        atomicAdd(&sh[((unsigned)dst[i]) >> R_LOG], 1u);
    __syncthreads();
    for (int k = threadIdx.x; k < KPAD; k += blockDim.x) {
        unsigned c = sh[k];
        offs0[(size_t)bid * KPAD + k] = c ? atomicAdd(&total[k], c) : 0u;
    }
}

// ---- pass 2: exclusive scan over bucket totals (<=4096), 1024 thr x 4 ------
__global__ void scan4_kernel(const unsigned* __restrict__ total,
                             unsigned* __restrict__ base,
                             int KPAD) {
    __shared__ unsigned s1[1024];
    __shared__ unsigned s2[1024];
    int t = threadIdx.x;
    unsigned v0 = (4 * t     < KPAD) ? total[4 * t]     : 0u;
    unsigned v1 = (4 * t + 1 < KPAD) ? total[4 * t + 1] : 0u;
    unsigned v2 = (4 * t + 2 < KPAD) ? total[4 * t + 2] : 0u;
    unsigned v3 = (4 * t + 3 < KPAD) ? total[4 * t + 3] : 0u;
    unsigned sum = v0 + v1 + v2 + v3;
    s1[t] = sum;
    __syncthreads();
    unsigned* cur = s1;
    unsigned* nxt = s2;
    for (int off = 1; off < 1024; off <<= 1) {
        unsigned x = cur[t];
        if (t >= off) x += cur[t - off];
        nxt[t] = x;
        __syncthreads();
        unsigned* tmp = cur; cur = nxt; nxt = tmp;
    }
    unsigned incl = cur[t];
    unsigned excl = incl - sum;
    base[4 * t]     = excl;
    base[4 * t + 1] = excl + v0;
    base[4 * t + 2] = excl + v0 + v1;
    base[4 * t + 3] = excl + v0 + v1 + v2;
    if (t == 1023) base[4096] = incl;
}

// ---- pass 3: scatter edges into 8B bucket-sorted records -------------------
// key = (dst_local:5 bits << 26) | src   (src < 2^26)
__global__ void scatter_kernel(const int* __restrict__ src,
                               const int* __restrict__ dst,
                               const float* __restrict__ w,
                               const unsigned* __restrict__ offs0,
                               const unsigned* __restrict__ base,
                               int2* __restrict__ recS,
                               int edges, int KPAD) {
    __shared__ unsigned loffs[MAX4K];
    int bid = blockIdx.x;
    for (int k = threadIdx.x; k < KPAD; k += blockDim.x)
        loffs[k] = base[k] + offs0[(size_t)bid * KPAD + k];
    __syncthreads();
    int start = bid * EPB;
    int end = min(edges, start + EPB);
    for (int i = start + threadIdx.x; i < end; i += blockDim.x) {
        int d = dst[i];
        int s = src[i];
        float wv = w[i];
        unsigned k = ((unsigned)d) >> R_LOG;
        unsigned pos = atomicAdd(&loffs[k], 1u);
        unsigned key = (((unsigned)d & (RNODES - 1)) << 26) | (unsigned)s;
        recS[pos] = make_int2((int)key, __float_as_int(wv));
    }
}

// ---- pass 4: per-bucket accumulate + fused finalize -------------------------
// PAIRED lanes: lanes (2p, 2p+1) process ONE record together. Lane parity q
// loads o_preT bytes [16q, 16q+16) of the record -> the pair's two float4
// loads fall in ONE 64B line within ONE instruction -> 1 line-transaction
// per record (vs 2 in R8). Each lane covers batches 4q..4q+3 (4 LDS atomics).
__global__ void accum_kernel(const int2* __restrict__ recS,
                             const unsigned* __restrict__ base,
                             const float* __restrict__ o_preT,   // (N,B)
                             const float* __restrict__ E,        // (B,N)
                             const float* __restrict__ chem_in,  // (B,N)
                             const float* __restrict__ thr,
                             const float* __restrict__ decay,
                             float* __restrict__ new_o,          // (B,N)
                             float* __restrict__ new_e,          // (B,N)
                             int N) {
    __shared__ float acc[RNODES * ASTR];
    __shared__ float e_lds[RNODES * ASTR];
    int k = blockIdx.x;
    int ns = k << R_LOG;
    int cnt = min(RNODES, N - ns);
    for (int i = threadIdx.x; i < RNODES * ASTR; i += blockDim.x) acc[i] = 0.f;
    for (int i = threadIdx.x; i < RNODES * BATCH; i += blockDim.x) {
        int b = i >> R_LOG;
        int n = i & (RNODES - 1);
        if (n < cnt) e_lds[n * ASTR + b] = E[(size_t)b * N + ns + n];
    }
    __syncthreads();

    unsigned b0 = base[k], b1 = base[k + 1];
    int q = threadIdx.x & 1;              // parity: which half of the record
    int p = threadIdx.x >> 1;             // pair index
    unsigned npairs = blockDim.x >> 1;    // pairs per block (128)
    int j0 = q << 2;                      // first batch this lane covers

    for (unsigned r0 = b0 + p; r0 < b1; r0 += 4u * npairs) {
        unsigned r1 = r0 + npairs, r2 = r0 + 2u * npairs, r3 = r0 + 3u * npairs;
        // guarded record loads; dummies carry w=0 -> zero contribution
        int2 rec0 = recS[r0];
        int2 rec1 = (r1 < b1) ? recS[r1] : make_int2(0, 0);
        int2 rec2 = (r2 < b1) ? recS[r2] : make_int2(0, 0);
        int2 rec3 = (r3 < b1) ? recS[r3] : make_int2(0, 0);
        // 4 independent paired gathers: each lane loads 16B of its record half
        float4 h0 = *(const float4*)&o_preT[((size_t)((unsigned)rec0.x & 0x3FFFFFFu) << 3) + (j0)];
        float4 h1 = *(const float4*)&o_preT[((size_t)((unsigned)rec1.x & 0x3FFFFFFu) << 3) + (j0)];
        float4 h2 = *(const float4*)&o_preT[((size_t)((unsigned)rec2.x & 0x3FFFFFFu) << 3) + (j0)];
        float4 h3 = *(const float4*)&o_preT[((size_t)((unsigned)rec3.x & 0x3FFFFFFu) << 3) + (j0)];
        int dl0 = (int)(((unsigned)rec0.x >> 26) & (RNODES - 1));
        int dl1 = (int)(((unsigned)rec1.x >> 26) & (RNODES - 1));
        int dl2 = (int)(((unsigned)rec2.x >> 26) & (RNODES - 1));
        int dl3 = (int)(((unsigned)rec3.x >> 26) & (RNODES - 1));
        float w0 = __int_as_float(rec0.y);
        float w1 = __int_as_float(rec1.y);
        float w2 = __int_as_float(rec2.y);
        float w3 = __int_as_float(rec3.y);
        float O0[4] = {h0.x, h0.y, h0.z, h0.w};
        float O1[4] = {h1.x, h1.y, h1.z, h1.w};
        float O2[4] = {h2.x, h2.y, h2.z, h2.w};
        float O3[4] = {h3.x, h3.y, h3.z, h3.w};
        #pragma unroll
        for (int j = 0; j < 4; ++j) {
            float En = e_lds[dl0 * ASTR + j0 + j];
            float df = O0[j] - En;
            float sg = (df > 0.f) ? 1.f : ((df < 0.f) ? -1.f : 0.f);
            atomicAdd(&acc[dl0 * ASTR + j0 + j], O0[j] * w0 * sg);
        }
        #pragma unroll
        for (int j = 0; j < 4; ++j) {
            float En = e_lds[dl1 * ASTR + j0 + j];
            float df = O1[j] - En;
            float sg = (df > 0.f) ? 1.f : ((df < 0.f) ? -1.f : 0.f);
            atomicAdd(&acc[dl1 * ASTR + j0 + j], O1[j] * w1 * sg);
        }
        #pragma unroll
        for (int j = 0; j < 4; ++j) {
            float En = e_lds[dl2 * ASTR + j0 + j];
            float df = O2[j] - En;
            float sg = (df > 0.f) ? 1.f : ((df < 0.f) ? -1.f : 0.f);
            atomicAdd(&acc[dl2 * ASTR + j0 + j], O2[j] * w2 * sg);
        }
        #pragma unroll
        for (int j = 0; j < 4; ++j) {
            float En = e_lds[dl3 * ASTR + j0 + j];
            float df = O3[j] - En;
            float sg = (df > 0.f) ? 1.f : ((df < 0.f) ? -1.f : 0.f);
            atomicAdd(&acc[dl3 * ASTR + j0 + j], O3[j] * w3 * sg);
        }
    }
    __syncthreads();

    // fused finalize: 32 nodes x 8 batches = 256 elems, one per thread
    for (int i = threadIdx.x; i < RNODES * BATCH; i += blockDim.x) {
        int b = i >> R_LOG;
        int n = i & (RNODES - 1);
        if (n >= cnt) continue;
        float e = e_lds[n * ASTR + b];
        float S = e + chem_in[(size_t)b * N + ns + n] + acc[n * ASTR + b];
        S = fminf(fmaxf(S, CLAMP_MIN_F), CLAMP_MAX_F);
        float t  = thr[ns + n];
        float dc = decay[ns + n];
        bool gt = S > t;
        float no = fmaxf(S - t, 0.f);
        float ne = gt ? no : ((S == e) ? (e - dc) : S);
        new_o[(size_t)b * N + ns + n] = no;
        new_e[(size_t)b * N + ns + n] = ne;
    }
}

// ---------------- fallback: R3 atomic path ----------------------------------
__global__ void prep_kernel(const float* __restrict__ chem_in,
                            const float* __restrict__ o_pre,
                            const float* __restrict__ E,
                            float* __restrict__ chemT,
                            float* __restrict__ o_preT,
                            float* __restrict__ E_T,
                            int N) {
    int n = blockIdx.x * blockDim.x + threadIdx.x;
    if (n >= N) return;
    float c[BATCH], o[BATCH], ee[BATCH];
    #pragma unroll
    for (int b = 0; b < BATCH; ++b) {
        c[b]  = chem_in[b * N + n];
        o[b]  = o_pre[b * N + n];
        ee[b] = E[b * N + n];
    }
    float4* cp = (float4*)&chemT[(size_t)n * BATCH];
    cp[0] = make_float4(c[0], c[1], c[2], c[3]);
    cp[1] = make_float4(c[4], c[5], c[6], c[7]);
    float4* op = (float4*)&o_preT[(size_t)n * BATCH];
    op[0] = make_float4(o[0], o[1], o[2], o[3]);
    op[1] = make_float4(o[4], o[5], o[6], o[7]);
    float4* ep = (float4*)&E_T[(size_t)n * BATCH];
    ep[0] = make_float4(ee[0], ee[1], ee[2], ee[3]);
    ep[1] = make_float4(ee[4], ee[5], ee[6], ee[7]);
}
__global__ void edge_scatter_eb(const int* __restrict__ src,
                                const int* __restrict__ dst,
                                const float* __restrict__ w,
                                const float* __restrict__ o_preT,
                                const float* __restrict__ E_T,
                                float* __restrict__ chemT,
                                int edges) {
    int t = blockIdx.x * blockDim.x + threadIdx.x;
    int e = t >> 3;
    int b = t & 7;
    if (e >= edges) return;
    int s = src[e]; int d = dst[e]; float we = w[e];
    float Oj = o_preT[(size_t)s * BATCH + b];
    float En = E_T[(size_t)d * BATCH + b];
    float diff = Oj - En;
    float sg = (diff > 0.0f) ? 1.0f : ((diff < 0.0f) ? -1.0f : 0.0f);
    atomicAdd(&chemT[(size_t)d * BATCH + b], Oj * we * sg);
}
__global__ void finalize_nb(const float* __restrict__ E,
                            const float* __restrict__ chemT,
                            const float* __restrict__ thr,
                            const float* __restrict__ decay,
                            float* __restrict__ new_o,
                            float* __restrict__ new_e, int N) {
    int n = blockIdx.x * blockDim.x + threadIdx.x;
    if (n >= N) return;
    const float4* cp = (const float4*)&chemT[(size_t)n * BATCH];
    float4 c0 = cp[0], c1 = cp[1];
    float c[BATCH] = {c0.x, c0.y, c0.z, c0.w, c1.x, c1.y, c1.z, c1.w};
    float t = thr[n];
    float dc = decay[n];
    #pragma unroll
    for (int b = 0; b < BATCH; ++b) {
        int i = b * N + n;
        float e = E[i];
        float S = fminf(fmaxf(e + c[b], CLAMP_MIN_F), CLAMP_MAX_F);
        bool gt = S > t;
        float no = fmaxf(S - t, 0.0f);
        float ne = gt ? no : ((S == e) ? (e - dc) : S);
        new_o[i] = no;
        new_e[i] = ne;
    }
}

static inline size_t align256(size_t x) { return (x + 255) & ~(size_t)255; }

extern "C" void kernel_launch(void* const* d_in, const int* in_sizes, int n_in,
                              void* d_out, int out_size, void* d_ws, size_t ws_size,
                              hipStream_t stream) {
    const float* chem_influence = (const float*)d_in[0];
    const float* E              = (const float*)d_in[1];
    const int*   src            = (const int*)d_in[3];
    const int*   dst            = (const int*)d_in[4];
    const float* w              = (const float*)d_in[5];
    const float* o_pre          = (const float*)d_in[6];
    const float* threshold      = (const float*)d_in[7];
    const float* decay          = (const float*)d_in[8];

    const int edges = in_sizes[3];
    const int BN    = in_sizes[0];   // B * N
    const int N     = in_sizes[7];   // threshold is (N,)

    float* new_o = (float*)d_out;
    float* new_e = (float*)d_out + BN;

    const int TB = 256;
    int nblk = (N + TB - 1) / TB;

    const int K    = (N + RNODES - 1) >> R_LOG;        // buckets (32 nodes)
    const int KPAD = (K + 63) & ~63;
    const int NB   = (edges + EPB - 1) / EPB;          // binning blocks

    // ws layout
    size_t off = 0;
    size_t opreT_off  = off; off += align256((size_t)BN * 4);
    size_t base_off   = off; off += align256((size_t)(MAX4K + 1) * 4);
    size_t total_off  = off; off += align256((size_t)MAX4K * 4);
    size_t offs0_off  = off; off += align256((size_t)NB * KPAD * 4);
    size_t rec_off    = off; off += align256((size_t)edges * 8);
    size_t need = off;

    char* wsb = (char*)d_ws;

    if (K <= MAX4K - 1 && ws_size >= need) {
        float*    o_preT = (float*)(wsb + opreT_off);
        unsigned* base   = (unsigned*)(wsb + base_off);
        unsigned* total  = (unsigned*)(wsb + total_off);
        unsigned* offs0  = (unsigned*)(wsb + offs0_off);
        int2*     recS   = (int2*)(wsb + rec_off);

        prep_o_kernel<<<nblk, TB, 0, stream>>>(o_pre, o_preT, total, N);
        hist_reserve_kernel<<<NB, TB_BIN, 0, stream>>>(dst, total, offs0, edges, KPAD);
        scan4_kernel<<<1, 1024, 0, stream>>>(total, base, KPAD);
        scatter_kernel<<<NB, TB_BIN, 0, stream>>>(src, dst, w, offs0, base, recS, edges, KPAD);
        accum_kernel<<<K, TB, 0, stream>>>(recS, base, o_preT, E,
                                           chem_influence, threshold, decay,
                                           new_o, new_e, N);
    } else if (ws_size >= 3 * (size_t)BN * 4) {
        float* chemT  = (float*)d_ws;
        float* o_preT = chemT + BN;
        float* E_T    = o_preT + BN;
        prep_kernel<<<nblk, TB, 0, stream>>>(chem_influence, o_pre, E,
                                             chemT, o_preT, E_T, N);
        long long ethreads = (long long)edges * BATCH;
        int gblk = (int)((ethreads + TB - 1) / TB);
        edge_scatter_eb<<<gblk, TB, 0, stream>>>(src, dst, w, o_preT, E_T,
                                                 chemT, edges);
        finalize_nb<<<nblk, TB, 0, stream>>>(E, chemT, threshold, decay,
                                             new_o, new_e, N);
    }
}

// Round 10
// 214.716 us; speedup vs baseline: 1.7162x; 1.0112x over previous
//
#include <hip/hip_runtime.h>

#define CLAMP_MIN_F (-10.0f)
#define CLAMP_MAX_F (10.0f)
#define BATCH 8
#define R_LOG 5          // 32 nodes per bucket
#define RNODES 32
#define ASTR 9           // LDS row stride (pad 8 -> 9)
#define EPB 16384        // edges per binning block
#define TB_BIN 1024      // threads for hist/scatter
#define MAX4K 4096       // scan capacity (K must be <= 4095)

// ---- prep: transpose o_pre (B,N) -> (N,B); zero bucket totals --------------
__global__ void prep_o_kernel(const float* __restrict__ o_pre,
                              float* __restrict__ o_preT,
                              unsigned* __restrict__ total,
                              int N) {
    int n = blockIdx.x * blockDim.x + threadIdx.x;
    if (n < MAX4K) total[n] = 0u;
    if (n >= N) return;
    float o[BATCH];
    #pragma unroll
    for (int b = 0; b < BATCH; ++b) o[b] = o_pre[b * N + n];
    float4* op = (float4*)&o_preT[(size_t)n * BATCH];
    op[0] = make_float4(o[0], o[1], o[2], o[3]);
    op[1] = make_float4(o[4], o[5], o[6], o[7]);
}

// ---- pass 1: per-block histogram + direct space reservation ----------------
__global__ void hist_reserve_kernel(const int* __restrict__ dst,
                                    unsigned* __restrict__ total,
                                    unsigned* __restrict__ offs0,
                                    int edges, int KPAD) {
    __shared__ unsigned sh[MAX4K];
    int bid = blockIdx.x;
    for (int k = threadIdx.x; k < KPAD; k += blockDim.x) sh[k] = 0u;
    __syncthreads();
    int start = bid * EPB;
    int end = min(edges, start + EPB);
    for (int i = start + threadIdx.x; i < end; i += blockDim.x)
        atomicAdd(&sh[((unsigned)dst[i]) >> R_LOG], 1u);
    __syncthreads();
    for (int k = threadIdx.x; k < KPAD; k += blockDim.x) {
        unsigned c = sh[k];
        offs0[(size_t)bid * KPAD + k] = c ? atomicAdd(&total[k], c) : 0u;
    }
}

// ---- pass 2: exclusive scan over bucket totals (<=4096), 1024 thr x 4 ------
__global__ void scan4_kernel(const unsigned* __restrict__ total,
                             unsigned* __restrict__ base,
                             int KPAD) {
    __shared__ unsigned s1[1024];
    __shared__ unsigned s2[1024];
    int t = threadIdx.x;
    unsigned v0 = (4 * t     < KPAD) ? total[4 * t]     : 0u;
    unsigned v1 = (4 * t + 1 < KPAD) ? total[4 * t + 1] : 0u;
    unsigned v2 = (4 * t + 2 < KPAD) ? total[4 * t + 2] : 0u;
    unsigned v3 = (4 * t + 3 < KPAD) ? total[4 * t + 3] : 0u;
    unsigned sum = v0 + v1 + v2 + v3;
    s1[t] = sum;
    __syncthreads();
    unsigned* cur = s1;
    unsigned* nxt = s2;
    for (int off = 1; off < 1024; off <<= 1) {
        unsigned x = cur[t];
        if (t >= off) x += cur[t - off];
        nxt[t] = x;
        __syncthreads();
        unsigned* tmp = cur; cur = nxt; nxt = tmp;
    }
    unsigned incl = cur[t];
    unsigned excl = incl - sum;
    base[4 * t]     = excl;
    base[4 * t + 1] = excl + v0;
    base[4 * t + 2] = excl + v0 + v1;
    base[4 * t + 3] = excl + v0 + v1 + v2;
    if (t == 1023) base[4096] = incl;
}

// ---- pass 3: scatter edges into 8B bucket-sorted records -------------------
// key = (dst_local:5 bits << 26) | src   (src < 2^26)
__global__ void scatter_kernel(const int* __restrict__ src,
                               const int* __restrict__ dst,
                               const float* __restrict__ w,
                               const unsigned* __restrict__ offs0,
                               const unsigned* __restrict__ base,
                               int2* __restrict__ recS,
                               int edges, int KPAD) {
    __shared__ unsigned loffs[MAX4K];
    int bid = blockIdx.x;
    for (int k = threadIdx.x; k < KPAD; k += blockDim.x)
        loffs[k] = base[k] + offs0[(size_t)bid * KPAD + k];
    __syncthreads();
    int start = bid * EPB;
    int end = min(edges, start + EPB);
    for (int i = start + threadIdx.x; i < end; i += blockDim.x) {
        int d = dst[i];
        int s = src[i];
        float wv = w[i];
        unsigned k = ((unsigned)d) >> R_LOG;
        unsigned pos = atomicAdd(&loffs[k], 1u);
        unsigned key = (((unsigned)d & (RNODES - 1)) << 26) | (unsigned)s;
        recS[pos] = make_int2((int)key, __float_as_int(wv));
    }
}

// ---- pass 4: per-bucket accumulate + fused finalize -------------------------
// 8-lane-GROUP per record: lane b reads o_preT[src*8+b] -- 8 consecutive
// dwords within ONE 32B sector in ONE instruction -> merges to a single
// memory request per record (R3/R6-verified coalescing). E is staged in LDS,
// so the gather stream is the ONLY random request stream: 3.2M requests.
// 4 independent chains per group for MLP.
__global__ void accum_kernel(const int2* __restrict__ recS,
                             const unsigned* __restrict__ base,
                             const float* __restrict__ o_preT,   // (N,B)
                             const float* __restrict__ E,        // (B,N)
                             const float* __restrict__ chem_in,  // (B,N)
                             const float* __restrict__ thr,
                             const float* __restrict__ decay,
                             float* __restrict__ new_o,          // (B,N)
                             float* __restrict__ new_e,          // (B,N)
                             int N) {
    __shared__ float acc[RNODES * ASTR];
    __shared__ float e_lds[RNODES * ASTR];
    int k = blockIdx.x;
    int ns = k << R_LOG;
    int cnt = min(RNODES, N - ns);
    for (int i = threadIdx.x; i < RNODES * ASTR; i += blockDim.x) acc[i] = 0.f;
    for (int i = threadIdx.x; i < RNODES * BATCH; i += blockDim.x) {
        int b = i >> R_LOG;
        int n = i & (RNODES - 1);
        if (n < cnt) e_lds[n * ASTR + b] = E[(size_t)b * N + ns + n];
    }
    __syncthreads();

    unsigned b0 = base[k], b1 = base[k + 1];
    int b = threadIdx.x & 7;              // batch lane within group
    int g = threadIdx.x >> 3;             // group index (0..31)
    unsigned ng = blockDim.x >> 3;        // groups per block (32)

    for (unsigned r0 = b0 + g; r0 < b1; r0 += 4u * ng) {
        unsigned r1 = r0 + ng, r2 = r0 + 2u * ng, r3 = r0 + 3u * ng;
        // record loads: 8 lanes same address -> broadcast (1 request each)
        int2 rec0 = recS[r0];
        int2 rec1 = (r1 < b1) ? recS[r1] : make_int2(0, 0);
        int2 rec2 = (r2 < b1) ? recS[r2] : make_int2(0, 0);
        int2 rec3 = (r3 < b1) ? recS[r3] : make_int2(0, 0);
        // 4 independent merged gathers: 8 lanes x 4B consecutive = 1 request
        float Oj0 = o_preT[((size_t)((unsigned)rec0.x & 0x3FFFFFFu) << 3) + b];
        float Oj1 = o_preT[((size_t)((unsigned)rec1.x & 0x3FFFFFFu) << 3) + b];
        float Oj2 = o_preT[((size_t)((unsigned)rec2.x & 0x3FFFFFFu) << 3) + b];
        float Oj3 = o_preT[((size_t)((unsigned)rec3.x & 0x3FFFFFFu) << 3) + b];
        int dl0 = (int)(((unsigned)rec0.x >> 26) & (RNODES - 1));
        int dl1 = (int)(((unsigned)rec1.x >> 26) & (RNODES - 1));
        int dl2 = (int)(((unsigned)rec2.x >> 26) & (RNODES - 1));
        int dl3 = (int)(((unsigned)rec3.x >> 26) & (RNODES - 1));
        float w0 = __int_as_float(rec0.y);
        float w1 = __int_as_float(rec1.y);
        float w2 = __int_as_float(rec2.y);
        float w3 = __int_as_float(rec3.y);
        {
            float En = e_lds[dl0 * ASTR + b];
            float df = Oj0 - En;
            float sg = (df > 0.f) ? 1.f : ((df < 0.f) ? -1.f : 0.f);
            atomicAdd(&acc[dl0 * ASTR + b], Oj0 * w0 * sg);
        }
        {
            float En = e_lds[dl1 * ASTR + b];
            float df = Oj1 - En;
            float sg = (df > 0.f) ? 1.f : ((df < 0.f) ? -1.f : 0.f);
            atomicAdd(&acc[dl1 * ASTR + b], Oj1 * w1 * sg);
        }
        {
            float En = e_lds[dl2 * ASTR + b];
            float df = Oj2 - En;
            float sg = (df > 0.f) ? 1.f : ((df < 0.f) ? -1.f : 0.f);
            atomicAdd(&acc[dl2 * ASTR + b], Oj2 * w2 * sg);
        }
        {
            float En = e_lds[dl3 * ASTR + b];
            float df = Oj3 - En;
            float sg = (df > 0.f) ? 1.f : ((df < 0.f) ? -1.f : 0.f);
            atomicAdd(&acc[dl3 * ASTR + b], Oj3 * w3 * sg);
        }
    }
    __syncthreads();

    // fused finalize: 32 nodes x 8 batches = 256 elems, one per thread
    for (int i = threadIdx.x; i < RNODES * BATCH; i += blockDim.x) {
        int bb = i >> R_LOG;
        int n = i & (RNODES - 1);
        if (n >= cnt) continue;
        float e = e_lds[n * ASTR + bb];
        float S = e + chem_in[(size_t)bb * N + ns + n] + acc[n * ASTR + bb];
        S = fminf(fmaxf(S, CLAMP_MIN_F), CLAMP_MAX_F);
        float t  = thr[ns + n];
        float dc = decay[ns + n];
        bool gt = S > t;
        float no = fmaxf(S - t, 0.f);
        float ne = gt ? no : ((S == e) ? (e - dc) : S);
        new_o[(size_t)bb * N + ns + n] = no;
        new_e[(size_t)bb * N + ns + n] = ne;
    }
}

// ---------------- fallback: R3 atomic path ----------------------------------
__global__ void prep_kernel(const float* __restrict__ chem_in,
                            const float* __restrict__ o_pre,
                            const float* __restrict__ E,
                            float* __restrict__ chemT,
                            float* __restrict__ o_preT,
                            float* __restrict__ E_T,
                            int N) {
    int n = blockIdx.x * blockDim.x + threadIdx.x;
    if (n >= N) return;
    float c[BATCH], o[BATCH], ee[BATCH];
    #pragma unroll
    for (int b = 0; b < BATCH; ++b) {
        c[b]  = chem_in[b * N + n];
        o[b]  = o_pre[b * N + n];
        ee[b] = E[b * N + n];
    }
    float4* cp = (float4*)&chemT[(size_t)n * BATCH];
    cp[0] = make_float4(c[0], c[1], c[2], c[3]);
    cp[1] = make_float4(c[4], c[5], c[6], c[7]);
    float4* op = (float4*)&o_preT[(size_t)n * BATCH];
    op[0] = make_float4(o[0], o[1], o[2], o[3]);
    op[1] = make_float4(o[4], o[5], o[6], o[7]);
    float4* ep = (float4*)&E_T[(size_t)n * BATCH];
    ep[0] = make_float4(ee[0], ee[1], ee[2], ee[3]);
    ep[1] = make_float4(ee[4], ee[5], ee[6], ee[7]);
}
__global__ void edge_scatter_eb(const int* __restrict__ src,
                                const int* __restrict__ dst,
                                const float* __restrict__ w,
                                const float* __restrict__ o_preT,
                                const float* __restrict__ E_T,
                                float* __restrict__ chemT,
                                int edges) {
    int t = blockIdx.x * blockDim.x + threadIdx.x;
    int e = t >> 3;
    int b = t & 7;
    if (e >= edges) return;
    int s = src[e]; int d = dst[e]; float we = w[e];
    float Oj = o_preT[(size_t)s * BATCH + b];
    float En = E_T[(size_t)d * BATCH + b];
    float diff = Oj - En;
    float sg = (diff > 0.0f) ? 1.0f : ((diff < 0.0f) ? -1.0f : 0.0f);
    atomicAdd(&chemT[(size_t)d * BATCH + b], Oj * we * sg);
}
__global__ void finalize_nb(const float* __restrict__ E,
                            const float* __restrict__ chemT,
                            const float* __restrict__ thr,
                            const float* __restrict__ decay,
                            float* __restrict__ new_o,
                            float* __restrict__ new_e, int N) {
    int n = blockIdx.x * blockDim.x + threadIdx.x;
    if (n >= N) return;
    const float4* cp = (const float4*)&chemT[(size_t)n * BATCH];
    float4 c0 = cp[0], c1 = cp[1];
    float c[BATCH] = {c0.x, c0.y, c0.z, c0.w, c1.x, c1.y, c1.z, c1.w};
    float t = thr[n];
    float dc = decay[n];
    #pragma unroll
    for (int b = 0; b < BATCH; ++b) {
        int i = b * N + n;
        float e = E[i];
        float S = fminf(fmaxf(e + c[b], CLAMP_MIN_F), CLAMP_MAX_F);
        bool gt = S > t;
        float no = fmaxf(S - t, 0.0f);
        float ne = gt ? no : ((S == e) ? (e - dc) : S);
        new_o[i] = no;
        new_e[i] = ne;
    }
}

static inline size_t align256(size_t x) { return (x + 255) & ~(size_t)255; }

extern "C" void kernel_launch(void* const* d_in, const int* in_sizes, int n_in,
                              void* d_out, int out_size, void* d_ws, size_t ws_size,
                              hipStream_t stream) {
    const float* chem_influence = (const float*)d_in[0];
    const float* E              = (const float*)d_in[1];
    const int*   src            = (const int*)d_in[3];
    const int*   dst            = (const int*)d_in[4];
    const float* w              = (const float*)d_in[5];
    const float* o_pre          = (const float*)d_in[6];
    const float* threshold      = (const float*)d_in[7];
    const float* decay          = (const float*)d_in[8];

    const int edges = in_sizes[3];
    const int BN    = in_sizes[0];   // B * N
    const int N     = in_sizes[7];   // threshold is (N,)

    float* new_o = (float*)d_out;
    float* new_e = (float*)d_out + BN;

    const int TB = 256;
    int nblk = (N + TB - 1) / TB;

    const int K    = (N + RNODES - 1) >> R_LOG;        // buckets (32 nodes)
    const int KPAD = (K + 63) & ~63;
    const int NB   = (edges + EPB - 1) / EPB;          // binning blocks

    // ws layout
    size_t off = 0;
    size_t opreT_off  = off; off += align256((size_t)BN * 4);
    size_t base_off   = off; off += align256((size_t)(MAX4K + 1) * 4);
    size_t total_off  = off; off += align256((size_t)MAX4K * 4);
    size_t offs0_off  = off; off += align256((size_t)NB * KPAD * 4);
    size_t rec_off    = off; off += align256((size_t)edges * 8);
    size_t need = off;

    char* wsb = (char*)d_ws;

    if (K <= MAX4K - 1 && ws_size >= need) {
        float*    o_preT = (float*)(wsb + opreT_off);
        unsigned* base   = (unsigned*)(wsb + base_off);
        unsigned* total  = (unsigned*)(wsb + total_off);
        unsigned* offs0  = (unsigned*)(wsb + offs0_off);
        int2*     recS   = (int2*)(wsb + rec_off);

        prep_o_kernel<<<nblk, TB, 0, stream>>>(o_pre, o_preT, total, N);
        hist_reserve_kernel<<<NB, TB_BIN, 0, stream>>>(dst, total, offs0, edges, KPAD);
        scan4_kernel<<<1, 1024, 0, stream>>>(total, base, KPAD);
        scatter_kernel<<<NB, TB_BIN, 0, stream>>>(src, dst, w, offs0, base, recS, edges, KPAD);
        accum_kernel<<<K, TB, 0, stream>>>(recS, base, o_preT, E,
                                           chem_influence, threshold, decay,
                                           new_o, new_e, N);
    } else if (ws_size >= 3 * (size_t)BN * 4) {
        float* chemT  = (float*)d_ws;
        float* o_preT = chemT + BN;
        float* E_T    = o_preT + BN;
        prep_kernel<<<nblk, TB, 0, stream>>>(chem_influence, o_pre, E,
                                             chemT, o_preT, E_T, N);
        long long ethreads = (long long)edges * BATCH;
        int gblk = (int)((ethreads + TB - 1) / TB);
        edge_scatter_eb<<<gblk, TB, 0, stream>>>(src, dst, w, o_preT, E_T,
                                                 chemT, edges);
        finalize_nb<<<nblk, TB, 0, stream>>>(E, chemT, threshold, decay,
                                             new_o, new_e, N);
    }
}